// Round 8
// baseline (323.612 us; speedup 1.0000x reference)
//
#include <hip/hip_runtime.h>
#include <hip/hip_bf16.h>

// MSAttention on MI355X. R8: register-only flash attention exploiting S-symmetry.
//  S = scale*Q^T Q is SYMMETRIC -> compute S-tile as A=Q_j, B=Q_i so C-layout col = i.
//  Each lane owns ONE i-column: softmax state is scalar; P stays in registers and feeds
//  PV (O^T = V^T P^T) as B-frags directly via the window-pair K=32 embedding
//  j(k) = 32*wp + 16*(jj>>2) + 4*quad + (jj&3). Zero LDS / barriers / shuffles for P.
// ws layout (exactly 32 MB):
//   @0   Y   f32 [8][512][1024] 16 MB  (mm_in -> convs -> prep)   then Ob bf16 [8192][512] 8 MB
//   @16  tmp f32 4 MB (convs)                                     then Ybc bf16 8 MB (prep out)
//   @24  Ybt bf16 [128][1024][32] 8 MB (prep out)

#define DIMM 512
#define NTOK 1024
#define CC   128
#define DD   32
#define BB   8
#define EPSB 1e-5f
#define SCALE_ATT 0.17677669529663687f   // 32^-0.5
#define K2EXP (SCALE_ATT * 1.4426950408889634f)  // scale * log2(e), folded into exp2
#define TJ 128

typedef __attribute__((ext_vector_type(8))) short short8;
typedef __attribute__((ext_vector_type(4))) float f32x4;

__device__ __forceinline__ unsigned short f2bf(float f) {
    unsigned int x = __float_as_uint(f);
    unsigned int r = x + 0x7fffu + ((x >> 16) & 1u);   // RNE, finite inputs
    return (unsigned short)(r >> 16);
}
__device__ __forceinline__ unsigned int f2bf2(float lo, float hi) {
    return (unsigned int)f2bf(lo) | ((unsigned int)f2bf(hi) << 16);
}

// ---------------- K1: inconv GEMM (MFMA bf16, inline f32->bf16 staging) + BN1 ----------------
__global__ __launch_bounds__(256) void k_mm_in(
    const float* __restrict__ w_in,   // [512][512]
    const float* __restrict__ x,      // [8192][512]
    const float* __restrict__ g1, const float* __restrict__ b1,
    const float* __restrict__ m1, const float* __restrict__ v1,
    float* __restrict__ Y)
{
    __shared__ __align__(16) unsigned short As[128][72];
    __shared__ __align__(16) unsigned short Bs[128][72];
    const int r0 = blockIdx.x * 128;
    const int o0 = blockIdx.y * 128;
    const int b  = r0 >> 10, nloc0 = r0 & 1023;
    const int t = threadIdx.x, wid = t >> 6, lane = t & 63;
    const int l16 = lane & 15, quad = lane >> 4;
    const int wm = (wid >> 1) * 64, wn = (wid & 1) * 64;

    f32x4 acc[4][4];
#pragma unroll
    for (int i = 0; i < 4; i++)
#pragma unroll
        for (int j = 0; j < 4; j++) acc[i][j] = (f32x4){0.f, 0.f, 0.f, 0.f};

    for (int k0 = 0; k0 < DIMM; k0 += 64) {
        __syncthreads();
#pragma unroll
        for (int it = 0; it < 8; it++) {
            int flat = it * 256 + t;
            int row = flat >> 4, c4 = flat & 15;
            float4 w4 = *(const float4*)&w_in[(size_t)(o0 + row) * DIMM + k0 + c4 * 4];
            *(uint2*)&As[row][c4 * 4] = make_uint2(f2bf2(w4.x, w4.y), f2bf2(w4.z, w4.w));
            float4 x4 = *(const float4*)&x[(size_t)(r0 + row) * DIMM + k0 + c4 * 4];
            *(uint2*)&Bs[row][c4 * 4] = make_uint2(f2bf2(x4.x, x4.y), f2bf2(x4.z, x4.w));
        }
        __syncthreads();
#pragma unroll
        for (int kk = 0; kk < 2; kk++) {
            short8 af[4], bf_[4];
#pragma unroll
            for (int i = 0; i < 4; i++) af[i]  = *(const short8*)&As[wm + i * 16 + l16][kk * 32 + quad * 8];
#pragma unroll
            for (int j = 0; j < 4; j++) bf_[j] = *(const short8*)&Bs[wn + j * 16 + l16][kk * 32 + quad * 8];
#pragma unroll
            for (int i = 0; i < 4; i++)
#pragma unroll
                for (int j = 0; j < 4; j++)
                    acc[i][j] = __builtin_amdgcn_mfma_f32_16x16x32_bf16(af[i], bf_[j], acc[i][j], 0, 0, 0);
        }
    }
#pragma unroll
    for (int i = 0; i < 4; i++)
#pragma unroll
        for (int r = 0; r < 4; r++) {
            int o = o0 + wm + i * 16 + quad * 4 + r;
            float inv  = g1[o] / sqrtf(v1[o] + EPSB);
            float beta = b1[o] - m1[o] * inv;
#pragma unroll
            for (int j = 0; j < 4; j++) {
                int n = nloc0 + wn + j * 16 + l16;
                Y[((size_t)b * DIMM + o) * NTOK + n] = acc[i][j][r] * inv + beta;
            }
        }
}

// ---------------- K2: depthwise 3x3 (unchanged) ----------------
__global__ __launch_bounds__(256) void k_dwconv(
    const float* __restrict__ Y, const float* __restrict__ w_dw,
    float* __restrict__ tmp, int s)
{
    __shared__ float img[34][34];
    const int c = blockIdx.x;
    const int b = blockIdx.y;
    const int t = threadIdx.x;
    for (int i = t; i < 34 * 34; i += 256) (&img[0][0])[i] = 0.f;
    __syncthreads();
    const float* src0 = Y + ((size_t)b * DIMM + s * CC + c) * NTOK;
    const float* src1 = (s >= 2) ? (Y + ((size_t)b * DIMM + (s - 1) * CC + c) * NTOK) : nullptr;
    for (int p = t; p < NTOK; p += 256) {
        float v = src0[p];
        if (src1) v += src1[p];
        img[(p >> 5) + 1][(p & 31) + 1] = v;
    }
    __syncthreads();
    float w[9];
#pragma unroll
    for (int i = 0; i < 9; i++) w[i] = w_dw[c * 9 + i];
    for (int p = t; p < NTOK; p += 256) {
        int yy = p >> 5, xx = p & 31;
        float s0 = 0.f;
#pragma unroll
        for (int ky = 0; ky < 3; ky++)
#pragma unroll
            for (int kx = 0; kx < 3; kx++)
                s0 += img[yy + ky][xx + kx] * w[ky * 3 + kx];
        tmp[((size_t)b * CC + c) * NTOK + p] = s0;
    }
}

// ---------------- K3: pointwise 1x1 GEMM + BN2 (unchanged) ----------------
__global__ __launch_bounds__(256) void k_pwconv(
    const float* __restrict__ tmp, const float* __restrict__ w_pw,
    const float* __restrict__ g2, const float* __restrict__ b2,
    const float* __restrict__ m2, const float* __restrict__ v2,
    float* __restrict__ Y, int s)
{
    __shared__ float Wt[32][33];
    __shared__ float Tt[32][33];
    const int b  = blockIdx.z;
    const int o0 = blockIdx.y * 32;
    const int n0 = blockIdx.x * 32;
    const int t  = threadIdx.x;
    const int tx = t & 15, ty = t >> 4;
    const int lr = t >> 5, lc = t & 31;
    float acc[2][2] = {{0.f, 0.f}, {0.f, 0.f}};
    for (int k0 = 0; k0 < CC; k0 += 32) {
        __syncthreads();
#pragma unroll
        for (int r = 0; r < 4; r++) {
            int row = lr + r * 8;
            Wt[row][lc] = w_pw[(size_t)(o0 + row) * CC + k0 + lc];
            Tt[row][lc] = tmp[((size_t)b * CC + k0 + row) * NTOK + n0 + lc];
        }
        __syncthreads();
#pragma unroll
        for (int k = 0; k < 32; k++) {
            float wv[2] = {Wt[ty][k], Wt[ty + 16][k]};
            float tv[2] = {Tt[k][tx], Tt[k][tx + 16]};
            acc[0][0] += wv[0] * tv[0]; acc[0][1] += wv[0] * tv[1];
            acc[1][0] += wv[1] * tv[0]; acc[1][1] += wv[1] * tv[1];
        }
    }
#pragma unroll
    for (int q = 0; q < 2; q++) {
        int o = o0 + ty + 16 * q;
        float inv  = g2[o] / sqrtf(v2[o] + EPSB);
        float beta = b2[o] - m2[o] * inv;
#pragma unroll
        for (int r = 0; r < 2; r++) {
            int n = n0 + tx + 16 * r;
            Y[((size_t)b * DIMM + s * CC + o) * NTOK + n] = acc[q][r] * inv + beta;
        }
    }
}

// ---------------- K3.5: prep — Y f32 -> Ybc (bf16 ch-major) + Ybt (bf16 token-major/group) ----
__global__ __launch_bounds__(256) void k_prep(
    const float* __restrict__ Y,
    unsigned short* __restrict__ Ybc,   // [8][512][1024]
    unsigned short* __restrict__ Ybt)   // [128][1024][32]
{
    __shared__ float T[32][129];
    const int n0 = blockIdx.x * 128;
    const int g  = blockIdx.y;
    const int b = g >> 4, s = (g >> 2) & 3, h = g & 3;
    const int cb = s * CC + h * DD;
    const int t = threadIdx.x;
#pragma unroll
    for (int k = 0; k < 8; k++) {
        int idx = k * 256 + t;
        int d = idx >> 6, jp = (idx & 63) * 2;
        float2 v = *(const float2*)&Y[((size_t)b * DIMM + cb + d) * NTOK + n0 + jp];
        T[d][jp] = v.x; T[d][jp + 1] = v.y;
        *(unsigned int*)&Ybc[((size_t)b * DIMM + cb + d) * NTOK + n0 + jp] = f2bf2(v.x, v.y);
    }
    __syncthreads();
#pragma unroll
    for (int k = 0; k < 8; k++) {
        int idx = k * 256 + t;
        int n = idx >> 4, dp = (idx & 15) * 2;
        *(unsigned int*)&Ybt[((size_t)g * NTOK + n0 + n) * DD + dp] = f2bf2(T[dp][n], T[dp + 1][n]);
    }
}

// ---------------- K4: register-only MFMA flash attention (S symmetric) ----------------
// grid 2048: g = blk & 127 (XCD-affine), ib = blk >> 7. Wave owns 16 i-columns (i = base+l16).
// S-tile: A = Q_j (Qt rows), B = Q_i -> C col = i (lane&15), row = j (quad*4+r).
// Softmax: scalar m,l per lane; in-lane tree + shfl_xor(16,32).
// PV: O^T = V^T P^T, one K=32 MFMA per 32-j window-pair; B-frag = lane's own packed p.
__global__ __launch_bounds__(256) void k_attn(
    const unsigned short* __restrict__ Ybt,
    const unsigned short* __restrict__ Ybc,
    unsigned short* __restrict__ Ob)
{
    const int blk = blockIdx.x;
    const int g = blk & 127, ib = blk >> 7;
    const int b = g >> 4, s = (g >> 2) & 3, h = g & 3;
    const int cb = s * CC + h * DD;
    const unsigned short* Qt = Ybt + (size_t)g * NTOK * DD;          // [token][d]
    const unsigned short* Qc = Ybc + ((size_t)b * DIMM + cb) * NTOK; // [d][token]
    const int t = threadIdx.x;
    const int wid = t >> 6, lane = t & 63;
    const int l16 = lane & 15, quad = lane >> 4;
    const int i = ib * 64 + wid * 16 + l16;      // this lane's token column

    // B-frag for S (i side), resident: B[k=d=quad*8+jj][n=i=l16]
    const short8 qi = *(const short8*)&Qt[(size_t)i * DD + quad * 8];

    float m_run = -INFINITY, l_run = 0.f;
    f32x4 oacc[2] = {{0.f,0.f,0.f,0.f},{0.f,0.f,0.f,0.f}};
    const f32x4 zero4 = {0.f, 0.f, 0.f, 0.f};

    for (int j0 = 0; j0 < NTOK; j0 += TJ) {
        // S: sacc[jb][r] = S[j0+jb*16+quad*4+r][i]  (C col = i, row = j_local)
        f32x4 sacc[8];
#pragma unroll
        for (int jb = 0; jb < 8; jb++) {
            short8 qj = *(const short8*)&Qt[(size_t)(j0 + jb * 16 + l16) * DD + quad * 8];
            sacc[jb] = __builtin_amdgcn_mfma_f32_16x16x32_bf16(qj, qi, zero4, 0, 0, 0);
        }
        // tile max: in-lane 32 + cross-quad (j spans quads; i fixed per l16)
        float mx = fmaxf(fmaxf(sacc[0][0], sacc[0][1]), fmaxf(sacc[0][2], sacc[0][3]));
#pragma unroll
        for (int jb = 1; jb < 8; jb++) {
            float m2_ = fmaxf(fmaxf(sacc[jb][0], sacc[jb][1]), fmaxf(sacc[jb][2], sacc[jb][3]));
            mx = fmaxf(mx, m2_);
        }
        mx = fmaxf(mx, __shfl_xor(mx, 16));
        mx = fmaxf(mx, __shfl_xor(mx, 32));

        float mn = fmaxf(m_run, mx);
        float al = exp2f((m_run - mn) * K2EXP);   // 0 on first tile
        m_run = mn;
        float mnk = mn * K2EXP;

        // exp (exp2 with folded scale), truncate to bf16 (perm), consistent row-sum
        unsigned int pk[16];
        float rs = 0.f;
#pragma unroll
        for (int jb = 0; jb < 8; jb++) {
            float p0 = exp2f(fmaf(sacc[jb][0], K2EXP, -mnk));
            float p1 = exp2f(fmaf(sacc[jb][1], K2EXP, -mnk));
            float p2 = exp2f(fmaf(sacc[jb][2], K2EXP, -mnk));
            float p3 = exp2f(fmaf(sacc[jb][3], K2EXP, -mnk));
            rs += __uint_as_float(__float_as_uint(p0) & 0xffff0000u);
            rs += __uint_as_float(__float_as_uint(p1) & 0xffff0000u);
            rs += __uint_as_float(__float_as_uint(p2) & 0xffff0000u);
            rs += __uint_as_float(__float_as_uint(p3) & 0xffff0000u);
            pk[jb * 2]     = __builtin_amdgcn_perm(__float_as_uint(p1), __float_as_uint(p0), 0x07060302u);
            pk[jb * 2 + 1] = __builtin_amdgcn_perm(__float_as_uint(p3), __float_as_uint(p2), 0x07060302u);
        }
        rs += __shfl_xor(rs, 16);
        rs += __shfl_xor(rs, 32);
        l_run = l_run * al + rs;
#pragma unroll
        for (int dblk = 0; dblk < 2; dblk++)
#pragma unroll
            for (int r = 0; r < 4; r++) oacc[dblk][r] *= al;

        // PV: window-pair wp covers j = j0+wp*32 .. +31 in ONE K=32 MFMA.
        // slot jj: j(k) = j0 + wp*32 + 16*(jj>>2) + quad*4 + (jj&3); B dwords = lane's pk.
#pragma unroll
        for (int wp = 0; wp < 4; wp++) {
            short8 pb;
            ((unsigned int*)&pb)[0] = pk[wp * 4 + 0];
            ((unsigned int*)&pb)[1] = pk[wp * 4 + 1];
            ((unsigned int*)&pb)[2] = pk[wp * 4 + 2];
            ((unsigned int*)&pb)[3] = pk[wp * 4 + 3];
#pragma unroll
            for (int dblk = 0; dblk < 2; dblk++) {
                const unsigned short* ar = &Qc[(size_t)(dblk * 16 + l16) * NTOK + j0 + wp * 32 + quad * 4];
                short8 af;
                ((uint2*)&af)[0] = *(const uint2*)ar;          // slots 0..3: j offset +0
                ((uint2*)&af)[1] = *(const uint2*)(ar + 16);   // slots 4..7: j offset +16
                oacc[dblk] = __builtin_amdgcn_mfma_f32_16x16x32_bf16(af, pb, oacc[dblk], 0, 0, 0);
            }
        }
    }

    // epilogue: oacc[dblk][r] = O^T[d = dblk*16+quad*4+r][i] -> Ob[b][i][cb+d], 4 consecutive d
    float invl = 1.f / l_run;
#pragma unroll
    for (int dblk = 0; dblk < 2; dblk++) {
        uint2 pkd;
        pkd.x = f2bf2(oacc[dblk][0] * invl, oacc[dblk][1] * invl);
        pkd.y = f2bf2(oacc[dblk][2] * invl, oacc[dblk][3] * invl);
        *(uint2*)&Ob[((size_t)b * NTOK + i) * DIMM + cb + dblk * 16 + quad * 4] = pkd;
    }
}

// ---------------- K5: out-proj GEMM (A=Ob bf16 direct, B=w_out f32 inline-cvt), f32 out ----
__global__ __launch_bounds__(256) void k_mm_out(
    const unsigned short* __restrict__ Oin,  // [8192][512] bf16
    const float* __restrict__ w_out,         // [512][512] f32
    float* __restrict__ out)
{
    __shared__ __align__(16) unsigned short As[128][72];
    __shared__ __align__(16) unsigned short Bs[128][72];
    const int r0 = blockIdx.x * 128;
    const int o0 = blockIdx.y * 128;
    const int t = threadIdx.x, wid = t >> 6, lane = t & 63;
    const int l16 = lane & 15, quad = lane >> 4;
    const int wm = (wid >> 1) * 64, wn = (wid & 1) * 64;

    f32x4 acc[4][4];
#pragma unroll
    for (int i = 0; i < 4; i++)
#pragma unroll
        for (int j = 0; j < 4; j++) acc[i][j] = (f32x4){0.f, 0.f, 0.f, 0.f};

    for (int k0 = 0; k0 < DIMM; k0 += 64) {
        __syncthreads();
#pragma unroll
        for (int q = 0; q < 4; q++) {
            int flat = q * 256 + t;
            int row = flat >> 3, c8 = flat & 7;
            *(short8*)&As[row][c8 * 8] = *(const short8*)&Oin[(size_t)(r0 + row) * DIMM + k0 + c8 * 8];
        }
#pragma unroll
        for (int it = 0; it < 8; it++) {
            int flat = it * 256 + t;
            int row = flat >> 4, c4 = flat & 15;
            float4 w4 = *(const float4*)&w_out[(size_t)(o0 + row) * DIMM + k0 + c4 * 4];
            *(uint2*)&Bs[row][c4 * 4] = make_uint2(f2bf2(w4.x, w4.y), f2bf2(w4.z, w4.w));
        }
        __syncthreads();
#pragma unroll
        for (int kk = 0; kk < 2; kk++) {
            short8 af[4], bf_[4];
#pragma unroll
            for (int i = 0; i < 4; i++) af[i]  = *(const short8*)&As[wm + i * 16 + l16][kk * 32 + quad * 8];
#pragma unroll
            for (int j = 0; j < 4; j++) bf_[j] = *(const short8*)&Bs[wn + j * 16 + l16][kk * 32 + quad * 8];
#pragma unroll
            for (int i = 0; i < 4; i++)
#pragma unroll
                for (int j = 0; j < 4; j++)
                    acc[i][j] = __builtin_amdgcn_mfma_f32_16x16x32_bf16(af[i], bf_[j], acc[i][j], 0, 0, 0);
        }
    }
#pragma unroll
    for (int i = 0; i < 4; i++)
#pragma unroll
        for (int r = 0; r < 4; r++) {
            int rr = r0 + wm + i * 16 + quad * 4 + r;
#pragma unroll
            for (int j = 0; j < 4; j++) {
                int o = o0 + wn + j * 16 + l16;
                out[(size_t)rr * DIMM + o] = acc[i][j][r];
            }
        }
}

extern "C" void kernel_launch(void* const* d_in, const int* in_sizes, int n_in,
                              void* d_out, int out_size, void* d_ws, size_t ws_size,
                              hipStream_t stream)
{
    const float* x    = (const float*)d_in[0];
    const float* w_in = (const float*)d_in[1];
    const float* g1   = (const float*)d_in[2];
    const float* b1   = (const float*)d_in[3];
    const float* m1   = (const float*)d_in[4];
    const float* v1   = (const float*)d_in[5];
    const float* wdw  = (const float*)d_in[6];
    const float* wpw  = (const float*)d_in[7];
    const float* g2   = (const float*)d_in[8];
    const float* b2   = (const float*)d_in[9];
    const float* m2   = (const float*)d_in[10];
    const float* v2   = (const float*)d_in[11];
    const float* wout = (const float*)d_in[12];
    float* out = (float*)d_out;

    char* base = (char*)d_ws;
    float*          Y   = (float*)base;                                  // 16 MB (dies at prep)
    unsigned short* Ob  = (unsigned short*)base;                         // 8 MB  (attn out, over Y)
    float*          tmp = (float*)(base + (size_t)16 * 1024 * 1024);     // 4 MB  (convs)
    unsigned short* Ybc = (unsigned short*)(base + (size_t)16 * 1024 * 1024); // 8 MB (after tmp dies)
    unsigned short* Ybt = (unsigned short*)(base + (size_t)24 * 1024 * 1024); // 8 MB

    k_mm_in<<<dim3(64, 4), 256, 0, stream>>>(w_in, x, g1, b1, m1, v1, Y);
    for (int s = 1; s <= 3; s++) {
        k_dwconv<<<dim3(CC, BB), 256, 0, stream>>>(Y, wdw, tmp, s);
        k_pwconv<<<dim3(32, 4, 8), 256, 0, stream>>>(tmp, wpw, g2, b2, m2, v2, Y, s);
    }
    k_prep<<<dim3(8, 128), 256, 0, stream>>>(Y, Ybc, Ybt);
    k_attn<<<dim3(2048), 256, 0, stream>>>(Ybt, Ybc, Ob);
    k_mm_out<<<dim3(64, 4), 256, 0, stream>>>(Ob, wout, out);
}

// Round 9
// 255.650 us; speedup vs baseline: 1.2658x; 1.2658x over previous
//
#include <hip/hip_runtime.h>
#include <hip/hip_bf16.h>

// MSAttention on MI355X. R9: R8's register-only symmetric-S flash attention, with the PV
// A-operand (V^T) PRE-SWIZZLED into MFMA fragment order by k_prep (Vp), so every VMEM load
// in k_attn is a coalesced 16B/lane load. R8's 8B stride-2KB gathers saturated the TA
// address pipe (both pipes idle at 39% occupancy) — this removes them.
// ws layout (exactly 32 MB):
//   @0   Y   f32 [8][512][1024] 16 MB (mm_in -> convs -> prep)   then Ob bf16 [8192][512] 8 MB
//   @16  tmp f32 4 MB (convs)             then Vp bf16 [128][8jt][8sub][64lane][8] 8 MB (prep)
//   @24  Qt (Ybt) bf16 [128][1024][32] 8 MB (prep)

#define DIMM 512
#define NTOK 1024
#define CC   128
#define DD   32
#define BB   8
#define EPSB 1e-5f
#define SCALE_ATT 0.17677669529663687f   // 32^-0.5
#define K2EXP (SCALE_ATT * 1.4426950408889634f)  // scale * log2(e), folded into exp2
#define TJ 128

typedef __attribute__((ext_vector_type(8))) short short8;
typedef __attribute__((ext_vector_type(4))) float f32x4;

__device__ __forceinline__ unsigned short f2bf(float f) {
    unsigned int x = __float_as_uint(f);
    unsigned int r = x + 0x7fffu + ((x >> 16) & 1u);   // RNE, finite inputs
    return (unsigned short)(r >> 16);
}
__device__ __forceinline__ unsigned int f2bf2(float lo, float hi) {
    return (unsigned int)f2bf(lo) | ((unsigned int)f2bf(hi) << 16);
}

// ---------------- K1: inconv GEMM (MFMA bf16, inline f32->bf16 staging) + BN1 ----------------
__global__ __launch_bounds__(256) void k_mm_in(
    const float* __restrict__ w_in,   // [512][512]
    const float* __restrict__ x,      // [8192][512]
    const float* __restrict__ g1, const float* __restrict__ b1,
    const float* __restrict__ m1, const float* __restrict__ v1,
    float* __restrict__ Y)
{
    __shared__ __align__(16) unsigned short As[128][72];
    __shared__ __align__(16) unsigned short Bs[128][72];
    const int r0 = blockIdx.x * 128;
    const int o0 = blockIdx.y * 128;
    const int b  = r0 >> 10, nloc0 = r0 & 1023;
    const int t = threadIdx.x, wid = t >> 6, lane = t & 63;
    const int l16 = lane & 15, quad = lane >> 4;
    const int wm = (wid >> 1) * 64, wn = (wid & 1) * 64;

    f32x4 acc[4][4];
#pragma unroll
    for (int i = 0; i < 4; i++)
#pragma unroll
        for (int j = 0; j < 4; j++) acc[i][j] = (f32x4){0.f, 0.f, 0.f, 0.f};

    for (int k0 = 0; k0 < DIMM; k0 += 64) {
        __syncthreads();
#pragma unroll
        for (int it = 0; it < 8; it++) {
            int flat = it * 256 + t;
            int row = flat >> 4, c4 = flat & 15;
            float4 w4 = *(const float4*)&w_in[(size_t)(o0 + row) * DIMM + k0 + c4 * 4];
            *(uint2*)&As[row][c4 * 4] = make_uint2(f2bf2(w4.x, w4.y), f2bf2(w4.z, w4.w));
            float4 x4 = *(const float4*)&x[(size_t)(r0 + row) * DIMM + k0 + c4 * 4];
            *(uint2*)&Bs[row][c4 * 4] = make_uint2(f2bf2(x4.x, x4.y), f2bf2(x4.z, x4.w));
        }
        __syncthreads();
#pragma unroll
        for (int kk = 0; kk < 2; kk++) {
            short8 af[4], bf_[4];
#pragma unroll
            for (int i = 0; i < 4; i++) af[i]  = *(const short8*)&As[wm + i * 16 + l16][kk * 32 + quad * 8];
#pragma unroll
            for (int j = 0; j < 4; j++) bf_[j] = *(const short8*)&Bs[wn + j * 16 + l16][kk * 32 + quad * 8];
#pragma unroll
            for (int i = 0; i < 4; i++)
#pragma unroll
                for (int j = 0; j < 4; j++)
                    acc[i][j] = __builtin_amdgcn_mfma_f32_16x16x32_bf16(af[i], bf_[j], acc[i][j], 0, 0, 0);
        }
    }
#pragma unroll
    for (int i = 0; i < 4; i++)
#pragma unroll
        for (int r = 0; r < 4; r++) {
            int o = o0 + wm + i * 16 + quad * 4 + r;
            float inv  = g1[o] / sqrtf(v1[o] + EPSB);
            float beta = b1[o] - m1[o] * inv;
#pragma unroll
            for (int j = 0; j < 4; j++) {
                int n = nloc0 + wn + j * 16 + l16;
                Y[((size_t)b * DIMM + o) * NTOK + n] = acc[i][j][r] * inv + beta;
            }
        }
}

// ---------------- K2: depthwise 3x3 (unchanged) ----------------
__global__ __launch_bounds__(256) void k_dwconv(
    const float* __restrict__ Y, const float* __restrict__ w_dw,
    float* __restrict__ tmp, int s)
{
    __shared__ float img[34][34];
    const int c = blockIdx.x;
    const int b = blockIdx.y;
    const int t = threadIdx.x;
    for (int i = t; i < 34 * 34; i += 256) (&img[0][0])[i] = 0.f;
    __syncthreads();
    const float* src0 = Y + ((size_t)b * DIMM + s * CC + c) * NTOK;
    const float* src1 = (s >= 2) ? (Y + ((size_t)b * DIMM + (s - 1) * CC + c) * NTOK) : nullptr;
    for (int p = t; p < NTOK; p += 256) {
        float v = src0[p];
        if (src1) v += src1[p];
        img[(p >> 5) + 1][(p & 31) + 1] = v;
    }
    __syncthreads();
    float w[9];
#pragma unroll
    for (int i = 0; i < 9; i++) w[i] = w_dw[c * 9 + i];
    for (int p = t; p < NTOK; p += 256) {
        int yy = p >> 5, xx = p & 31;
        float s0 = 0.f;
#pragma unroll
        for (int ky = 0; ky < 3; ky++)
#pragma unroll
            for (int kx = 0; kx < 3; kx++)
                s0 += img[yy + ky][xx + kx] * w[ky * 3 + kx];
        tmp[((size_t)b * CC + c) * NTOK + p] = s0;
    }
}

// ---------------- K3: pointwise 1x1 GEMM + BN2 (unchanged) ----------------
__global__ __launch_bounds__(256) void k_pwconv(
    const float* __restrict__ tmp, const float* __restrict__ w_pw,
    const float* __restrict__ g2, const float* __restrict__ b2,
    const float* __restrict__ m2, const float* __restrict__ v2,
    float* __restrict__ Y, int s)
{
    __shared__ float Wt[32][33];
    __shared__ float Tt[32][33];
    const int b  = blockIdx.z;
    const int o0 = blockIdx.y * 32;
    const int n0 = blockIdx.x * 32;
    const int t  = threadIdx.x;
    const int tx = t & 15, ty = t >> 4;
    const int lr = t >> 5, lc = t & 31;
    float acc[2][2] = {{0.f, 0.f}, {0.f, 0.f}};
    for (int k0 = 0; k0 < CC; k0 += 32) {
        __syncthreads();
#pragma unroll
        for (int r = 0; r < 4; r++) {
            int row = lr + r * 8;
            Wt[row][lc] = w_pw[(size_t)(o0 + row) * CC + k0 + lc];
            Tt[row][lc] = tmp[((size_t)b * CC + k0 + row) * NTOK + n0 + lc];
        }
        __syncthreads();
#pragma unroll
        for (int k = 0; k < 32; k++) {
            float wv[2] = {Wt[ty][k], Wt[ty + 16][k]};
            float tv[2] = {Tt[k][tx], Tt[k][tx + 16]};
            acc[0][0] += wv[0] * tv[0]; acc[0][1] += wv[0] * tv[1];
            acc[1][0] += wv[1] * tv[0]; acc[1][1] += wv[1] * tv[1];
        }
    }
#pragma unroll
    for (int q = 0; q < 2; q++) {
        int o = o0 + ty + 16 * q;
        float inv  = g2[o] / sqrtf(v2[o] + EPSB);
        float beta = b2[o] - m2[o] * inv;
#pragma unroll
        for (int r = 0; r < 2; r++) {
            int n = n0 + tx + 16 * r;
            Y[((size_t)b * DIMM + s * CC + o) * NTOK + n] = acc[q][r] * inv + beta;
        }
    }
}

// ---------------- K3.5: prep — Y f32 -> Qt (token-major bf16) + Vp (PV A-frag order) ----------
// Vp entry layout: Vp[g][jt][sub=wp*2+dblk][lane=quad*16+l16][8 shorts], where the 8 shorts are
// V[d=dblk*16+l16][j = jt*128 + wp*32 + quad*4 + {0,1,2,3,16,17,18,19}] — exactly the MFMA
// A-fragment (k = quad*8+jj) for the PV window-pair embedding. One 16B load/lane in k_attn.
__global__ __launch_bounds__(256) void k_prep(
    const float* __restrict__ Y,
    unsigned short* __restrict__ Vp,    // [128][8][8][64][8]
    unsigned short* __restrict__ Qt)    // [128][1024][32]
{
    __shared__ float T[32][129];
    const int jt = blockIdx.x;
    const int n0 = jt * 128;
    const int g  = blockIdx.y;
    const int b = g >> 4, s = (g >> 2) & 3, h = g & 3;
    const int cb = s * CC + h * DD;
    const int t = threadIdx.x;
#pragma unroll
    for (int k = 0; k < 8; k++) {
        int idx = k * 256 + t;
        int d = idx >> 6, jp = (idx & 63) * 2;
        float2 v = *(const float2*)&Y[((size_t)b * DIMM + cb + d) * NTOK + n0 + jp];
        T[d][jp] = v.x; T[d][jp + 1] = v.y;
    }
    __syncthreads();
    // Qt: token-major
#pragma unroll
    for (int k = 0; k < 8; k++) {
        int idx = k * 256 + t;
        int n = idx >> 4, dp = (idx & 15) * 2;
        *(unsigned int*)&Qt[((size_t)g * NTOK + n0 + n) * DD + dp] = f2bf2(T[dp][n], T[dp + 1][n]);
    }
    // Vp: fragment-order (512 entries x 16B)
#pragma unroll
    for (int e2 = 0; e2 < 2; e2++) {
        int e = e2 * 256 + t;
        int sub = e >> 6, lane = e & 63;
        int quad = lane >> 4, l16 = lane & 15;
        int d  = (sub & 1) * 16 + l16;
        int jb = (sub >> 1) * 32 + quad * 4;
        uint4 v;
        v.x = f2bf2(T[d][jb + 0],  T[d][jb + 1]);
        v.y = f2bf2(T[d][jb + 2],  T[d][jb + 3]);
        v.z = f2bf2(T[d][jb + 16], T[d][jb + 17]);
        v.w = f2bf2(T[d][jb + 18], T[d][jb + 19]);
        *(uint4*)&Vp[((((size_t)g * 8 + jt) * 8 + sub) * 64 + lane) * 8] = v;
    }
}

// ---------------- K4: register-only MFMA flash attention (S symmetric, coalesced) ----------
// grid 2048: g = blk & 127 (XCD-affine), ib = blk >> 7. Wave owns 16 i-columns (i = base+l16).
// S-tile: A = Q_j, B = Q_i -> C col = i, row = j. Scalar softmax state per lane.
// PV: O^T = V^T P^T; B-frag = lane's own packed p (registers); A-frag = ONE coalesced 16B
// load from Vp. Zero LDS, zero barriers.
__global__ __launch_bounds__(256) void k_attn(
    const unsigned short* __restrict__ Qtg,
    const unsigned short* __restrict__ Vp,
    unsigned short* __restrict__ Ob)
{
    const int blk = blockIdx.x;
    const int g = blk & 127, ib = blk >> 7;
    const int b = g >> 4, s = (g >> 2) & 3, h = g & 3;
    const int cb = s * CC + h * DD;
    const unsigned short* Qt = Qtg + (size_t)g * NTOK * DD;          // [token][d]
    const unsigned short* Vg = Vp + (size_t)g * 8 * 8 * 64 * 8;      // [jt][sub][lane][8]
    const int t = threadIdx.x;
    const int wid = t >> 6, lane = t & 63;
    const int l16 = lane & 15, quad = lane >> 4;
    const int i = ib * 64 + wid * 16 + l16;      // this lane's token column

    const short8 qi = *(const short8*)&Qt[(size_t)i * DD + quad * 8];

    float m_run = -INFINITY, l_run = 0.f;
    f32x4 oacc[2] = {{0.f,0.f,0.f,0.f},{0.f,0.f,0.f,0.f}};
    const f32x4 zero4 = {0.f, 0.f, 0.f, 0.f};

#pragma unroll 2
    for (int jt = 0; jt < 8; jt++) {
        const int j0 = jt * TJ;
        // S: sacc[jb][r] = S[j0+jb*16+quad*4+r][i]
        f32x4 sacc[8];
#pragma unroll
        for (int jb = 0; jb < 8; jb++) {
            short8 qj = *(const short8*)&Qt[(size_t)(j0 + jb * 16 + l16) * DD + quad * 8];
            sacc[jb] = __builtin_amdgcn_mfma_f32_16x16x32_bf16(qj, qi, zero4, 0, 0, 0);
        }
        float mx = fmaxf(fmaxf(sacc[0][0], sacc[0][1]), fmaxf(sacc[0][2], sacc[0][3]));
#pragma unroll
        for (int jb = 1; jb < 8; jb++) {
            float m2_ = fmaxf(fmaxf(sacc[jb][0], sacc[jb][1]), fmaxf(sacc[jb][2], sacc[jb][3]));
            mx = fmaxf(mx, m2_);
        }
        mx = fmaxf(mx, __shfl_xor(mx, 16));
        mx = fmaxf(mx, __shfl_xor(mx, 32));

        float mn = fmaxf(m_run, mx);
        float al = exp2f((m_run - mn) * K2EXP);   // 0 on first tile
        m_run = mn;
        float mnk = mn * K2EXP;

        unsigned int pk[16];
        float rs = 0.f;
#pragma unroll
        for (int jb = 0; jb < 8; jb++) {
            float p0 = exp2f(fmaf(sacc[jb][0], K2EXP, -mnk));
            float p1 = exp2f(fmaf(sacc[jb][1], K2EXP, -mnk));
            float p2 = exp2f(fmaf(sacc[jb][2], K2EXP, -mnk));
            float p3 = exp2f(fmaf(sacc[jb][3], K2EXP, -mnk));
            rs += __uint_as_float(__float_as_uint(p0) & 0xffff0000u);
            rs += __uint_as_float(__float_as_uint(p1) & 0xffff0000u);
            rs += __uint_as_float(__float_as_uint(p2) & 0xffff0000u);
            rs += __uint_as_float(__float_as_uint(p3) & 0xffff0000u);
            pk[jb * 2]     = __builtin_amdgcn_perm(__float_as_uint(p1), __float_as_uint(p0), 0x07060302u);
            pk[jb * 2 + 1] = __builtin_amdgcn_perm(__float_as_uint(p3), __float_as_uint(p2), 0x07060302u);
        }
        rs += __shfl_xor(rs, 16);
        rs += __shfl_xor(rs, 32);
        l_run = l_run * al + rs;
#pragma unroll
        for (int dblk = 0; dblk < 2; dblk++)
#pragma unroll
            for (int r = 0; r < 4; r++) oacc[dblk][r] *= al;

        // PV: one K=32 MFMA per (wp, dblk); A = coalesced Vp frag, B = lane's packed p.
#pragma unroll
        for (int wp = 0; wp < 4; wp++) {
            short8 pb;
            ((unsigned int*)&pb)[0] = pk[wp * 4 + 0];
            ((unsigned int*)&pb)[1] = pk[wp * 4 + 1];
            ((unsigned int*)&pb)[2] = pk[wp * 4 + 2];
            ((unsigned int*)&pb)[3] = pk[wp * 4 + 3];
#pragma unroll
            for (int dblk = 0; dblk < 2; dblk++) {
                short8 af = *(const short8*)&Vg[(((size_t)jt * 8 + wp * 2 + dblk) * 64 + lane) * 8];
                oacc[dblk] = __builtin_amdgcn_mfma_f32_16x16x32_bf16(af, pb, oacc[dblk], 0, 0, 0);
            }
        }
    }

    // epilogue: oacc[dblk][r] = O^T[d = dblk*16+quad*4+r][i] -> Ob[b][i][cb+d]
    float invl = 1.f / l_run;
#pragma unroll
    for (int dblk = 0; dblk < 2; dblk++) {
        uint2 pkd;
        pkd.x = f2bf2(oacc[dblk][0] * invl, oacc[dblk][1] * invl);
        pkd.y = f2bf2(oacc[dblk][2] * invl, oacc[dblk][3] * invl);
        *(uint2*)&Ob[((size_t)b * NTOK + i) * DIMM + cb + dblk * 16 + quad * 4] = pkd;
    }
}

// ---------------- K5: out-proj GEMM (A=Ob bf16 direct, B=w_out f32 inline-cvt), f32 out ----
__global__ __launch_bounds__(256) void k_mm_out(
    const unsigned short* __restrict__ Oin,  // [8192][512] bf16
    const float* __restrict__ w_out,         // [512][512] f32
    float* __restrict__ out)
{
    __shared__ __align__(16) unsigned short As[128][72];
    __shared__ __align__(16) unsigned short Bs[128][72];
    const int r0 = blockIdx.x * 128;
    const int o0 = blockIdx.y * 128;
    const int t = threadIdx.x, wid = t >> 6, lane = t & 63;
    const int l16 = lane & 15, quad = lane >> 4;
    const int wm = (wid >> 1) * 64, wn = (wid & 1) * 64;

    f32x4 acc[4][4];
#pragma unroll
    for (int i = 0; i < 4; i++)
#pragma unroll
        for (int j = 0; j < 4; j++) acc[i][j] = (f32x4){0.f, 0.f, 0.f, 0.f};

    for (int k0 = 0; k0 < DIMM; k0 += 64) {
        __syncthreads();
#pragma unroll
        for (int q = 0; q < 4; q++) {
            int flat = q * 256 + t;
            int row = flat >> 3, c8 = flat & 7;
            *(short8*)&As[row][c8 * 8] = *(const short8*)&Oin[(size_t)(r0 + row) * DIMM + k0 + c8 * 8];
        }
#pragma unroll
        for (int it = 0; it < 8; it++) {
            int flat = it * 256 + t;
            int row = flat >> 4, c4 = flat & 15;
            float4 w4 = *(const float4*)&w_out[(size_t)(o0 + row) * DIMM + k0 + c4 * 4];
            *(uint2*)&Bs[row][c4 * 4] = make_uint2(f2bf2(w4.x, w4.y), f2bf2(w4.z, w4.w));
        }
        __syncthreads();
#pragma unroll
        for (int kk = 0; kk < 2; kk++) {
            short8 af[4], bf_[4];
#pragma unroll
            for (int i = 0; i < 4; i++) af[i]  = *(const short8*)&As[wm + i * 16 + l16][kk * 32 + quad * 8];
#pragma unroll
            for (int j = 0; j < 4; j++) bf_[j] = *(const short8*)&Bs[wn + j * 16 + l16][kk * 32 + quad * 8];
#pragma unroll
            for (int i = 0; i < 4; i++)
#pragma unroll
                for (int j = 0; j < 4; j++)
                    acc[i][j] = __builtin_amdgcn_mfma_f32_16x16x32_bf16(af[i], bf_[j], acc[i][j], 0, 0, 0);
        }
    }
#pragma unroll
    for (int i = 0; i < 4; i++)
#pragma unroll
        for (int r = 0; r < 4; r++) {
            int rr = r0 + wm + i * 16 + quad * 4 + r;
#pragma unroll
            for (int j = 0; j < 4; j++) {
                int o = o0 + wn + j * 16 + l16;
                out[(size_t)rr * DIMM + o] = acc[i][j][r];
            }
        }
}

extern "C" void kernel_launch(void* const* d_in, const int* in_sizes, int n_in,
                              void* d_out, int out_size, void* d_ws, size_t ws_size,
                              hipStream_t stream)
{
    const float* x    = (const float*)d_in[0];
    const float* w_in = (const float*)d_in[1];
    const float* g1   = (const float*)d_in[2];
    const float* b1   = (const float*)d_in[3];
    const float* m1   = (const float*)d_in[4];
    const float* v1   = (const float*)d_in[5];
    const float* wdw  = (const float*)d_in[6];
    const float* wpw  = (const float*)d_in[7];
    const float* g2   = (const float*)d_in[8];
    const float* b2   = (const float*)d_in[9];
    const float* m2   = (const float*)d_in[10];
    const float* v2   = (const float*)d_in[11];
    const float* wout = (const float*)d_in[12];
    float* out = (float*)d_out;

    char* base = (char*)d_ws;
    float*          Y   = (float*)base;                                  // 16 MB (dies at prep)
    unsigned short* Ob  = (unsigned short*)base;                         // 8 MB  (attn out, over Y)
    float*          tmp = (float*)(base + (size_t)16 * 1024 * 1024);     // 4 MB  (convs)
    unsigned short* Vp  = (unsigned short*)(base + (size_t)16 * 1024 * 1024); // 8 MB (after tmp dies)
    unsigned short* Qt  = (unsigned short*)(base + (size_t)24 * 1024 * 1024); // 8 MB

    k_mm_in<<<dim3(64, 4), 256, 0, stream>>>(w_in, x, g1, b1, m1, v1, Y);
    for (int s = 1; s <= 3; s++) {
        k_dwconv<<<dim3(CC, BB), 256, 0, stream>>>(Y, wdw, tmp, s);
        k_pwconv<<<dim3(32, 4, 8), 256, 0, stream>>>(tmp, wpw, g2, b2, m2, v2, Y, s);
    }
    k_prep<<<dim3(8, 128), 256, 0, stream>>>(Y, Vp, Qt);
    k_attn<<<dim3(2048), 256, 0, stream>>>(Qt, Vp, Ob);
    k_mm_out<<<dim3(64, 4), 256, 0, stream>>>(Ob, wout, out);
}

// Round 10
// 228.266 us; speedup vs baseline: 1.4177x; 1.1200x over previous
//
#include <hip/hip_runtime.h>
#include <hip/hip_bf16.h>

// MSAttention on MI355X. R10:
//  - k_attn: row-sum via ones-MFMA (lacc) — removes 64 VALU + 2 shfl per tile; P-sums exactly
//    consistent with PV-MFMA's P-tilde. pb packed in place.
//  - k_pwconv -> k_mm_pw (MFMA, 128o x 64n, BK=64, inline f32->bf16 staging, fused BN2).
//  - everything else identical to R9 (255.6 us, absmax 0.117).
// ws layout (32 MB):
//   @0   Y   f32 [8][512][1024] 16 MB (mm_in -> convs -> prep)   then Ob bf16 [8192][512] 8 MB
//   @16  tmp f32 4 MB (convs)             then Vp bf16 [128][8jt][8sub][64lane][8] 8 MB (prep)
//   @24  Qt bf16 [128][1024][32] 8 MB (prep)

#define DIMM 512
#define NTOK 1024
#define CC   128
#define DD   32
#define BB   8
#define EPSB 1e-5f
#define SCALE_ATT 0.17677669529663687f   // 32^-0.5
#define K2EXP (SCALE_ATT * 1.4426950408889634f)  // scale * log2(e), folded into exp2
#define TJ 128

typedef __attribute__((ext_vector_type(8))) short short8;
typedef __attribute__((ext_vector_type(4))) float f32x4;

__device__ __forceinline__ unsigned short f2bf(float f) {
    unsigned int x = __float_as_uint(f);
    unsigned int r = x + 0x7fffu + ((x >> 16) & 1u);   // RNE, finite inputs
    return (unsigned short)(r >> 16);
}
__device__ __forceinline__ unsigned int f2bf2(float lo, float hi) {
    return (unsigned int)f2bf(lo) | ((unsigned int)f2bf(hi) << 16);
}

// ---------------- K1: inconv GEMM (MFMA bf16, inline f32->bf16 staging) + BN1 ----------------
__global__ __launch_bounds__(256) void k_mm_in(
    const float* __restrict__ w_in,   // [512][512]
    const float* __restrict__ x,      // [8192][512]
    const float* __restrict__ g1, const float* __restrict__ b1,
    const float* __restrict__ m1, const float* __restrict__ v1,
    float* __restrict__ Y)
{
    __shared__ __align__(16) unsigned short As[128][72];
    __shared__ __align__(16) unsigned short Bs[128][72];
    const int r0 = blockIdx.x * 128;
    const int o0 = blockIdx.y * 128;
    const int b  = r0 >> 10, nloc0 = r0 & 1023;
    const int t = threadIdx.x, wid = t >> 6, lane = t & 63;
    const int l16 = lane & 15, quad = lane >> 4;
    const int wm = (wid >> 1) * 64, wn = (wid & 1) * 64;

    f32x4 acc[4][4];
#pragma unroll
    for (int i = 0; i < 4; i++)
#pragma unroll
        for (int j = 0; j < 4; j++) acc[i][j] = (f32x4){0.f, 0.f, 0.f, 0.f};

    for (int k0 = 0; k0 < DIMM; k0 += 64) {
        __syncthreads();
#pragma unroll
        for (int it = 0; it < 8; it++) {
            int flat = it * 256 + t;
            int row = flat >> 4, c4 = flat & 15;
            float4 w4 = *(const float4*)&w_in[(size_t)(o0 + row) * DIMM + k0 + c4 * 4];
            *(uint2*)&As[row][c4 * 4] = make_uint2(f2bf2(w4.x, w4.y), f2bf2(w4.z, w4.w));
            float4 x4 = *(const float4*)&x[(size_t)(r0 + row) * DIMM + k0 + c4 * 4];
            *(uint2*)&Bs[row][c4 * 4] = make_uint2(f2bf2(x4.x, x4.y), f2bf2(x4.z, x4.w));
        }
        __syncthreads();
#pragma unroll
        for (int kk = 0; kk < 2; kk++) {
            short8 af[4], bf_[4];
#pragma unroll
            for (int i = 0; i < 4; i++) af[i]  = *(const short8*)&As[wm + i * 16 + l16][kk * 32 + quad * 8];
#pragma unroll
            for (int j = 0; j < 4; j++) bf_[j] = *(const short8*)&Bs[wn + j * 16 + l16][kk * 32 + quad * 8];
#pragma unroll
            for (int i = 0; i < 4; i++)
#pragma unroll
                for (int j = 0; j < 4; j++)
                    acc[i][j] = __builtin_amdgcn_mfma_f32_16x16x32_bf16(af[i], bf_[j], acc[i][j], 0, 0, 0);
        }
    }
#pragma unroll
    for (int i = 0; i < 4; i++)
#pragma unroll
        for (int r = 0; r < 4; r++) {
            int o = o0 + wm + i * 16 + quad * 4 + r;
            float inv  = g1[o] / sqrtf(v1[o] + EPSB);
            float beta = b1[o] - m1[o] * inv;
#pragma unroll
            for (int j = 0; j < 4; j++) {
                int n = nloc0 + wn + j * 16 + l16;
                Y[((size_t)b * DIMM + o) * NTOK + n] = acc[i][j][r] * inv + beta;
            }
        }
}

// ---------------- K2: depthwise 3x3 (unchanged) ----------------
__global__ __launch_bounds__(256) void k_dwconv(
    const float* __restrict__ Y, const float* __restrict__ w_dw,
    float* __restrict__ tmp, int s)
{
    __shared__ float img[34][34];
    const int c = blockIdx.x;
    const int b = blockIdx.y;
    const int t = threadIdx.x;
    for (int i = t; i < 34 * 34; i += 256) (&img[0][0])[i] = 0.f;
    __syncthreads();
    const float* src0 = Y + ((size_t)b * DIMM + s * CC + c) * NTOK;
    const float* src1 = (s >= 2) ? (Y + ((size_t)b * DIMM + (s - 1) * CC + c) * NTOK) : nullptr;
    for (int p = t; p < NTOK; p += 256) {
        float v = src0[p];
        if (src1) v += src1[p];
        img[(p >> 5) + 1][(p & 31) + 1] = v;
    }
    __syncthreads();
    float w[9];
#pragma unroll
    for (int i = 0; i < 9; i++) w[i] = w_dw[c * 9 + i];
    for (int p = t; p < NTOK; p += 256) {
        int yy = p >> 5, xx = p & 31;
        float s0 = 0.f;
#pragma unroll
        for (int ky = 0; ky < 3; ky++)
#pragma unroll
            for (int kx = 0; kx < 3; kx++)
                s0 += img[yy + ky][xx + kx] * w[ky * 3 + kx];
        tmp[((size_t)b * CC + c) * NTOK + p] = s0;
    }
}

// ---------------- K3: pointwise 1x1 via MFMA + BN2 ----------------
// ys[s][o][n] = BN2( sum_c w_pw[o][c] * tmp[b][c][n] ). Block: o-tile 128 x n-tile 64.
// grid (16 n-blocks, 8 b). K=128 in two BK=64 halves, inline f32->bf16 staging.
__global__ __launch_bounds__(256) void k_mm_pw(
    const float* __restrict__ tmp, const float* __restrict__ w_pw,
    const float* __restrict__ g2, const float* __restrict__ b2,
    const float* __restrict__ m2, const float* __restrict__ v2,
    float* __restrict__ Y, int s)
{
    __shared__ __align__(16) unsigned short As[128][72];  // [o][k]
    __shared__ __align__(16) unsigned short Bs[64][72];   // [n][k]
    const int n0 = blockIdx.x * 64;
    const int b  = blockIdx.y;
    const int t = threadIdx.x, wid = t >> 6, lane = t & 63;
    const int l16 = lane & 15, quad = lane >> 4;
    const int wm = (wid >> 1) * 64, wn = (wid & 1) * 32;

    f32x4 acc[4][2];
#pragma unroll
    for (int i = 0; i < 4; i++) { acc[i][0] = (f32x4){0.f,0.f,0.f,0.f}; acc[i][1] = (f32x4){0.f,0.f,0.f,0.f}; }

    for (int k0 = 0; k0 < CC; k0 += 64) {
        __syncthreads();
        // A: w_pw rows o=128, k-half 64 -> 2048 float4 chunks
#pragma unroll
        for (int it = 0; it < 8; it++) {
            int flat = it * 256 + t;
            int row = flat >> 4, c4 = flat & 15;
            float4 w4 = *(const float4*)&w_pw[(size_t)row * CC + k0 + c4 * 4];
            *(uint2*)&As[row][c4 * 4] = make_uint2(f2bf2(w4.x, w4.y), f2bf2(w4.z, w4.w));
        }
        // B: tmp [c][n] -> Bs[n][c] (LDS transpose), 64c x 16 float4-chunks
#pragma unroll
        for (int it = 0; it < 4; it++) {
            int flat = it * 256 + t;
            int c = flat >> 4, n4 = (flat & 15) * 4;
            float4 v = *(const float4*)&tmp[((size_t)b * CC + k0 + c) * NTOK + n0 + n4];
            Bs[n4 + 0][c] = f2bf(v.x);
            Bs[n4 + 1][c] = f2bf(v.y);
            Bs[n4 + 2][c] = f2bf(v.z);
            Bs[n4 + 3][c] = f2bf(v.w);
        }
        __syncthreads();
#pragma unroll
        for (int kk = 0; kk < 2; kk++) {
            short8 af[4], bf_[2];
#pragma unroll
            for (int i = 0; i < 4; i++) af[i]  = *(const short8*)&As[wm + i * 16 + l16][kk * 32 + quad * 8];
#pragma unroll
            for (int j = 0; j < 2; j++) bf_[j] = *(const short8*)&Bs[wn + j * 16 + l16][kk * 32 + quad * 8];
#pragma unroll
            for (int i = 0; i < 4; i++)
#pragma unroll
                for (int j = 0; j < 2; j++)
                    acc[i][j] = __builtin_amdgcn_mfma_f32_16x16x32_bf16(af[i], bf_[j], acc[i][j], 0, 0, 0);
        }
    }
#pragma unroll
    for (int i = 0; i < 4; i++)
#pragma unroll
        for (int r = 0; r < 4; r++) {
            int o = wm + i * 16 + quad * 4 + r;
            float inv  = g2[o] / sqrtf(v2[o] + EPSB);
            float beta = b2[o] - m2[o] * inv;
#pragma unroll
            for (int j = 0; j < 2; j++) {
                int n = n0 + wn + j * 16 + l16;
                Y[((size_t)b * DIMM + s * CC + o) * NTOK + n] = acc[i][j][r] * inv + beta;
            }
        }
}

// ---------------- K3.5: prep — Y f32 -> Qt (token-major bf16) + Vp (PV A-frag order) ----------
__global__ __launch_bounds__(256) void k_prep(
    const float* __restrict__ Y,
    unsigned short* __restrict__ Vp,    // [128][8][8][64][8]
    unsigned short* __restrict__ Qt)    // [128][1024][32]
{
    __shared__ float T[32][129];
    const int jt = blockIdx.x;
    const int n0 = jt * 128;
    const int g  = blockIdx.y;
    const int b = g >> 4, s = (g >> 2) & 3, h = g & 3;
    const int cb = s * CC + h * DD;
    const int t = threadIdx.x;
#pragma unroll
    for (int k = 0; k < 8; k++) {
        int idx = k * 256 + t;
        int d = idx >> 6, jp = (idx & 63) * 2;
        float2 v = *(const float2*)&Y[((size_t)b * DIMM + cb + d) * NTOK + n0 + jp];
        T[d][jp] = v.x; T[d][jp + 1] = v.y;
    }
    __syncthreads();
#pragma unroll
    for (int k = 0; k < 8; k++) {
        int idx = k * 256 + t;
        int n = idx >> 4, dp = (idx & 15) * 2;
        *(unsigned int*)&Qt[((size_t)g * NTOK + n0 + n) * DD + dp] = f2bf2(T[dp][n], T[dp + 1][n]);
    }
#pragma unroll
    for (int e2 = 0; e2 < 2; e2++) {
        int e = e2 * 256 + t;
        int sub = e >> 6, lane = e & 63;
        int quad = lane >> 4, l16 = lane & 15;
        int d  = (sub & 1) * 16 + l16;
        int jb = (sub >> 1) * 32 + quad * 4;
        uint4 v;
        v.x = f2bf2(T[d][jb + 0],  T[d][jb + 1]);
        v.y = f2bf2(T[d][jb + 2],  T[d][jb + 3]);
        v.z = f2bf2(T[d][jb + 16], T[d][jb + 17]);
        v.w = f2bf2(T[d][jb + 18], T[d][jb + 19]);
        *(uint4*)&Vp[((((size_t)g * 8 + jt) * 8 + sub) * 64 + lane) * 8] = v;
    }
}

// ---------------- K4: register-only MFMA flash attention (S symmetric, ones-MFMA row sums) ----
__global__ __launch_bounds__(256) void k_attn(
    const unsigned short* __restrict__ Qtg,
    const unsigned short* __restrict__ Vp,
    unsigned short* __restrict__ Ob)
{
    const int blk = blockIdx.x;
    const int g = blk & 127, ib = blk >> 7;
    const int b = g >> 4, s = (g >> 2) & 3, h = g & 3;
    const int cb = s * CC + h * DD;
    const unsigned short* Qt = Qtg + (size_t)g * NTOK * DD;          // [token][d]
    const unsigned short* Vg = Vp + (size_t)g * 8 * 8 * 64 * 8;      // [jt][sub][lane][8]
    const int t = threadIdx.x;
    const int wid = t >> 6, lane = t & 63;
    const int l16 = lane & 15, quad = lane >> 4;
    const int i = ib * 64 + wid * 16 + l16;      // this lane's token column

    const short8 qi = *(const short8*)&Qt[(size_t)i * DD + quad * 8];
    const short8 ones = {0x3F80, 0x3F80, 0x3F80, 0x3F80, 0x3F80, 0x3F80, 0x3F80, 0x3F80};

    float m_run = -INFINITY;
    f32x4 lacc = {0.f, 0.f, 0.f, 0.f};
    f32x4 oacc[2] = {{0.f,0.f,0.f,0.f},{0.f,0.f,0.f,0.f}};
    const f32x4 zero4 = {0.f, 0.f, 0.f, 0.f};

#pragma unroll 2
    for (int jt = 0; jt < 8; jt++) {
        const int j0 = jt * TJ;
        f32x4 sacc[8];
#pragma unroll
        for (int jb = 0; jb < 8; jb++) {
            short8 qj = *(const short8*)&Qt[(size_t)(j0 + jb * 16 + l16) * DD + quad * 8];
            sacc[jb] = __builtin_amdgcn_mfma_f32_16x16x32_bf16(qj, qi, zero4, 0, 0, 0);
        }
        float mx = fmaxf(fmaxf(sacc[0][0], sacc[0][1]), fmaxf(sacc[0][2], sacc[0][3]));
#pragma unroll
        for (int jb = 1; jb < 8; jb++) {
            float m2_ = fmaxf(fmaxf(sacc[jb][0], sacc[jb][1]), fmaxf(sacc[jb][2], sacc[jb][3]));
            mx = fmaxf(mx, m2_);
        }
        mx = fmaxf(mx, __shfl_xor(mx, 16));
        mx = fmaxf(mx, __shfl_xor(mx, 32));

        float mn = fmaxf(m_run, mx);
        float al = exp2f((m_run - mn) * K2EXP);   // 0 on first tile
        m_run = mn;
        float mnk = mn * K2EXP;

        // exp -> packed bf16 P directly into PV B-frags
        short8 pb[4];
#pragma unroll
        for (int jb = 0; jb < 8; jb++) {
            float p0 = exp2f(fmaf(sacc[jb][0], K2EXP, -mnk));
            float p1 = exp2f(fmaf(sacc[jb][1], K2EXP, -mnk));
            float p2 = exp2f(fmaf(sacc[jb][2], K2EXP, -mnk));
            float p3 = exp2f(fmaf(sacc[jb][3], K2EXP, -mnk));
            ((unsigned int*)&pb[jb >> 1])[(jb & 1) * 2]     =
                __builtin_amdgcn_perm(__float_as_uint(p1), __float_as_uint(p0), 0x07060302u);
            ((unsigned int*)&pb[jb >> 1])[(jb & 1) * 2 + 1] =
                __builtin_amdgcn_perm(__float_as_uint(p3), __float_as_uint(p2), 0x07060302u);
        }

        // rescale accumulators
#pragma unroll
        for (int r = 0; r < 4; r++) { oacc[0][r] *= al; oacc[1][r] *= al; lacc[r] *= al; }

        // PV + row-sum MFMAs: A = coalesced Vp frag (or ones), B = lane's packed P
#pragma unroll
        for (int wp = 0; wp < 4; wp++) {
            short8 af0 = *(const short8*)&Vg[(((size_t)jt * 8 + wp * 2 + 0) * 64 + lane) * 8];
            short8 af1 = *(const short8*)&Vg[(((size_t)jt * 8 + wp * 2 + 1) * 64 + lane) * 8];
            oacc[0] = __builtin_amdgcn_mfma_f32_16x16x32_bf16(af0, pb[wp], oacc[0], 0, 0, 0);
            oacc[1] = __builtin_amdgcn_mfma_f32_16x16x32_bf16(af1, pb[wp], oacc[1], 0, 0, 0);
            lacc    = __builtin_amdgcn_mfma_f32_16x16x32_bf16(ones, pb[wp], lacc, 0, 0, 0);
        }
    }

    // epilogue: oacc[dblk][r] = O^T[d][i]; l = lacc[0] (all rows of ones-MFMA D are equal)
    float invl = 1.f / lacc[0];
#pragma unroll
    for (int dblk = 0; dblk < 2; dblk++) {
        uint2 pkd;
        pkd.x = f2bf2(oacc[dblk][0] * invl, oacc[dblk][1] * invl);
        pkd.y = f2bf2(oacc[dblk][2] * invl, oacc[dblk][3] * invl);
        *(uint2*)&Ob[((size_t)b * NTOK + i) * DIMM + cb + dblk * 16 + quad * 4] = pkd;
    }
}

// ---------------- K5: out-proj GEMM (A=Ob bf16 direct, B=w_out f32 inline-cvt), f32 out ----
__global__ __launch_bounds__(256) void k_mm_out(
    const unsigned short* __restrict__ Oin,  // [8192][512] bf16
    const float* __restrict__ w_out,         // [512][512] f32
    float* __restrict__ out)
{
    __shared__ __align__(16) unsigned short As[128][72];
    __shared__ __align__(16) unsigned short Bs[128][72];
    const int r0 = blockIdx.x * 128;
    const int o0 = blockIdx.y * 128;
    const int t = threadIdx.x, wid = t >> 6, lane = t & 63;
    const int l16 = lane & 15, quad = lane >> 4;
    const int wm = (wid >> 1) * 64, wn = (wid & 1) * 64;

    f32x4 acc[4][4];
#pragma unroll
    for (int i = 0; i < 4; i++)
#pragma unroll
        for (int j = 0; j < 4; j++) acc[i][j] = (f32x4){0.f, 0.f, 0.f, 0.f};

    for (int k0 = 0; k0 < DIMM; k0 += 64) {
        __syncthreads();
#pragma unroll
        for (int q = 0; q < 4; q++) {
            int flat = q * 256 + t;
            int row = flat >> 3, c8 = flat & 7;
            *(short8*)&As[row][c8 * 8] = *(const short8*)&Oin[(size_t)(r0 + row) * DIMM + k0 + c8 * 8];
        }
#pragma unroll
        for (int it = 0; it < 8; it++) {
            int flat = it * 256 + t;
            int row = flat >> 4, c4 = flat & 15;
            float4 w4 = *(const float4*)&w_out[(size_t)(o0 + row) * DIMM + k0 + c4 * 4];
            *(uint2*)&Bs[row][c4 * 4] = make_uint2(f2bf2(w4.x, w4.y), f2bf2(w4.z, w4.w));
        }
        __syncthreads();
#pragma unroll
        for (int kk = 0; kk < 2; kk++) {
            short8 af[4], bf_[4];
#pragma unroll
            for (int i = 0; i < 4; i++) af[i]  = *(const short8*)&As[wm + i * 16 + l16][kk * 32 + quad * 8];
#pragma unroll
            for (int j = 0; j < 4; j++) bf_[j] = *(const short8*)&Bs[wn + j * 16 + l16][kk * 32 + quad * 8];
#pragma unroll
            for (int i = 0; i < 4; i++)
#pragma unroll
                for (int j = 0; j < 4; j++)
                    acc[i][j] = __builtin_amdgcn_mfma_f32_16x16x32_bf16(af[i], bf_[j], acc[i][j], 0, 0, 0);
        }
    }
#pragma unroll
    for (int i = 0; i < 4; i++)
#pragma unroll
        for (int r = 0; r < 4; r++) {
            int rr = r0 + wm + i * 16 + quad * 4 + r;
#pragma unroll
            for (int j = 0; j < 4; j++) {
                int o = o0 + wn + j * 16 + l16;
                out[(size_t)rr * DIMM + o] = acc[i][j][r];
            }
        }
}

extern "C" void kernel_launch(void* const* d_in, const int* in_sizes, int n_in,
                              void* d_out, int out_size, void* d_ws, size_t ws_size,
                              hipStream_t stream)
{
    const float* x    = (const float*)d_in[0];
    const float* w_in = (const float*)d_in[1];
    const float* g1   = (const float*)d_in[2];
    const float* b1   = (const float*)d_in[3];
    const float* m1   = (const float*)d_in[4];
    const float* v1   = (const float*)d_in[5];
    const float* wdw  = (const float*)d_in[6];
    const float* wpw  = (const float*)d_in[7];
    const float* g2   = (const float*)d_in[8];
    const float* b2   = (const float*)d_in[9];
    const float* m2   = (const float*)d_in[10];
    const float* v2   = (const float*)d_in[11];
    const float* wout = (const float*)d_in[12];
    float* out = (float*)d_out;

    char* base = (char*)d_ws;
    float*          Y   = (float*)base;                                  // 16 MB (dies at prep)
    unsigned short* Ob  = (unsigned short*)base;                         // 8 MB  (attn out, over Y)
    float*          tmp = (float*)(base + (size_t)16 * 1024 * 1024);     // 4 MB  (convs)
    unsigned short* Vp  = (unsigned short*)(base + (size_t)16 * 1024 * 1024); // 8 MB (after tmp dies)
    unsigned short* Qt  = (unsigned short*)(base + (size_t)24 * 1024 * 1024); // 8 MB

    k_mm_in<<<dim3(64, 4), 256, 0, stream>>>(w_in, x, g1, b1, m1, v1, Y);
    for (int s = 1; s <= 3; s++) {
        k_dwconv<<<dim3(CC, BB), 256, 0, stream>>>(Y, wdw, tmp, s);
        k_mm_pw<<<dim3(16, 8), 256, 0, stream>>>(tmp, wpw, g2, b2, m2, v2, Y, s);
    }
    k_prep<<<dim3(8, 128), 256, 0, stream>>>(Y, Vp, Qt);
    k_attn<<<dim3(2048), 256, 0, stream>>>(Qt, Vp, Ob);
    k_mm_out<<<dim3(64, 4), 256, 0, stream>>>(Ob, wout, out);
}